// Round 6
// baseline (37.284 us; speedup 1.0000x reference)
//
#include <hip/hip_runtime.h>
#include <hip/hip_bf16.h>

// Y[b,e,k,j] = sum_i X[b, ind[b,e,k], i] * W[e,i,j]
// X:[B,T,I] f32, ind:[B,E,K] int32, W:[E,I,J] f32 -> Y:[B,E,K,J] f32
#define B_ 8
#define T_ 8192
#define I_ 128
#define E_ 16
#define J_ 128
#define K_ 1024

typedef unsigned short u16;
typedef unsigned int   u32;
typedef __attribute__((ext_vector_type(8))) short s8v;   // 8 bf16 = 4 VGPRs
typedef __attribute__((ext_vector_type(4))) float f4v;   // MFMA accumulator

__device__ __forceinline__ u16 f2bf(float f) {
    union { __hip_bfloat16 h; u16 u; } v;
    v.h = __float2bfloat16(f);          // RNE, packs to v_cvt_pk_bf16_f32
    return v.u;
}

__device__ __forceinline__ void gload_lds16(const void* g, void* l) {
    __builtin_amdgcn_global_load_lds(
        (const __attribute__((address_space(1))) u32*)g,
        (__attribute__((address_space(3))) u32*)l, 16, 0, 0);
}

// ---- Prepass: write PRE-SWIZZLED bf16 W^T image per expert ----
// Image chunk c (16B): j = c>>4, i0 = (c&15)*8, holds bf16 W[e][i0..i0+7][j] at
// byte offset (c*16) ^ ((j&7)<<4). 64 blocks = (e, j-quarter), coalesced.
__global__ void convert_wt(const float* __restrict__ W, u16* __restrict__ Wt) {
    __shared__ float Wf[I_ * 33];        // [i][jl], jl=0..31, padded
    const int bid = blockIdx.x;          // e*4 + jq
    const int e   = bid >> 2;
    const int j0  = (bid & 3) * 32;
    const int t   = threadIdx.x;
    const float* We = W + (size_t)e * (I_ * J_);
#pragma unroll
    for (int u = 0; u < 4; ++u) {
        const int f4 = t + 256 * u;      // 0..1023
        const int i  = f4 >> 3;
        const int c  = f4 & 7;
        const float4 v = *reinterpret_cast<const float4*>(We + (size_t)i * J_ + j0 + c * 4);
        float* p = &Wf[i * 33 + c * 4];
        p[0] = v.x; p[1] = v.y; p[2] = v.z; p[3] = v.w;
    }
    __syncthreads();
    char* img = (char*)Wt + (size_t)e * (I_ * J_ * 2);
#pragma unroll
    for (int u2 = 0; u2 < 2; ++u2) {
        const int c  = t + 256 * u2;     // 0..511
        const int jl = c >> 4;
        const int j  = j0 + jl;
        const int i0 = (c & 15) * 8;
        s8v o;
#pragma unroll
        for (int u = 0; u < 8; ++u)
            o[u] = (short)f2bf(Wf[(i0 + u) * 33 + jl]);
        const int cimg = j * 16 + (c & 15);
        *reinterpret_cast<s8v*>(img + ((cimg * 16) ^ ((j & 7) << 4))) = o;
    }
}

// ---- Main: W in LDS (one stage, ONE barrier); X loaded per-lane direct from
// global (coalesced 128B/row segments), converted in-register, fed to MFMA.
// No Xs LDS, no barriers in the k-loop: waves free-run (TLP latency hiding).
// LDS 32KB, launch_bounds(256,4) -> 4 blocks/CU = 16 waves/CU.
template<bool PRE>
__global__ __launch_bounds__(256, 4)
void gather_mfma(const float* __restrict__ X, const int* __restrict__ ind,
                 const void* __restrict__ Wsrc, float* __restrict__ Y) {
    __shared__ u16 WsT[I_ * J_];     // swizzled W^T: W[j][i], byte^=((j&7)<<4)

    const int t    = threadIdx.x;
    const int wave = t >> 6;
    const int lane = t & 63;

    const int h  = blockIdx.x & 7;       // 8 double-tiles per (b,e)
    const int be = blockIdx.x >> 3;
    const int e  = be & (E_ - 1);
    const int b  = be >> 4;
    const int k0 = h * 128;              // 2 tiles of 64 rows

    // ---- Stage WsT ----
    if (PRE) {
        const char* Wimg = (const char*)Wsrc + (size_t)e * 32768;
#pragma unroll
        for (int u = 0; u < 8; ++u) {
            const int off = (wave * 8 + u) * 1024;   // wave-uniform LDS dest
            gload_lds16(Wimg + off + lane * 16, (char*)WsT + off);
        }
    } else {
        const float* We = (const float*)Wsrc + (size_t)e * (I_ * J_);
#pragma unroll
        for (int u = 0; u < 16; ++u) {
            const int f4i = t + 256 * u;
            const int i   = f4i >> 5;
            const int j0  = (f4i & 31) * 4;
            const float4 w4 = reinterpret_cast<const float4*>(We)[f4i];
            const float ws[4] = {w4.x, w4.y, w4.z, w4.w};
#pragma unroll
            for (int q = 0; q < 4; ++q) {
                const int j = j0 + q;
                *(u16*)((char*)WsT + ((j * 256 + i * 2) ^ ((j & 7) << 4))) = f2bf(ws[q]);
            }
        }
    }
    __syncthreads();     // the ONLY barrier: W image complete (drains vmcnt)

    // ---- Wave decomposition: wave = (rh = k-half, jh = j-half) ----
    const int rh  = wave >> 1;
    const int jh  = wave & 1;
    const int g   = lane >> 4;
    const int l15 = lane & 15;
    const int sx  = (lane & 7) << 4;
    const char* wb = (const char*)WsT + (size_t)(jh * 64 + l15) * 256;

    const float4* Xb = reinterpret_cast<const float4*>(X + (size_t)b * T_ * I_);
    const int indb = be * K_ + k0 + rh * 32 + l15;

    // Hoist all token indices (L2-hot, removes dependent chains in the loop)
    const int tokA0 = ind[indb];
    const int tokA1 = ind[indb + 16];
    const int tokB0 = ind[indb + 64];
    const int tokB1 = ind[indb + 80];

#pragma unroll
    for (int tile = 0; tile < 2; ++tile) {
        const float4* r0 = Xb + (size_t)(tile ? tokB0 : tokA0) * (I_ / 4);
        const float4* r1 = Xb + (size_t)(tile ? tokB1 : tokA1) * (I_ / 4);

        f4v acc[2][4];
#pragma unroll
        for (int tr = 0; tr < 2; ++tr)
#pragma unroll
            for (int nj = 0; nj < 4; ++nj)
#pragma unroll
                for (int rr = 0; rr < 4; ++rr) acc[tr][nj][rr] = 0.f;

#pragma unroll
        for (int s = 0; s < 4; ++s) {
            // Lane (g,l15): X[tok][i = s*32+g*8 .. +7] — 4 g-lanes cover 128B contiguous
            const float4 a0 = r0[s * 8 + g * 2], a1 = r0[s * 8 + g * 2 + 1];
            const float4 c0 = r1[s * 8 + g * 2], c1 = r1[s * 8 + g * 2 + 1];
            s8v x0, x1;
            x0[0] = (short)f2bf(a0.x); x0[1] = (short)f2bf(a0.y);
            x0[2] = (short)f2bf(a0.z); x0[3] = (short)f2bf(a0.w);
            x0[4] = (short)f2bf(a1.x); x0[5] = (short)f2bf(a1.y);
            x0[6] = (short)f2bf(a1.z); x0[7] = (short)f2bf(a1.w);
            x1[0] = (short)f2bf(c0.x); x1[1] = (short)f2bf(c0.y);
            x1[2] = (short)f2bf(c0.z); x1[3] = (short)f2bf(c0.w);
            x1[4] = (short)f2bf(c1.x); x1[5] = (short)f2bf(c1.y);
            x1[6] = (short)f2bf(c1.z); x1[7] = (short)f2bf(c1.w);

            const int off = (s * 64 + g * 16) ^ sx;   // W[j][same i-range], swizzled
#pragma unroll
            for (int nj = 0; nj < 4; ++nj) {
                const s8v wf = *reinterpret_cast<const s8v*>(wb + nj * 16 * 256 + off);
                acc[0][nj] = __builtin_amdgcn_mfma_f32_16x16x32_bf16(wf, x0, acc[0][nj], 0, 0, 0);
                acc[1][nj] = __builtin_amdgcn_mfma_f32_16x16x32_bf16(wf, x1, acc[1][nj], 0, 0, 0);
            }
        }

        // D: col(lane&15)=token-row, row(4g+rr)=j  ->  float4 along j
        float* Yb = Y + ((size_t)be * K_ + k0 + tile * 64) * J_;
#pragma unroll
        for (int tr = 0; tr < 2; ++tr) {
            float* rowp = Yb + (size_t)(rh * 32 + tr * 16 + l15) * J_ + jh * 64 + g * 4;
#pragma unroll
            for (int nj = 0; nj < 4; ++nj)
                *reinterpret_cast<f4v*>(rowp + nj * 16) = acc[tr][nj];
        }
    }
}

extern "C" void kernel_launch(void* const* d_in, const int* in_sizes, int n_in,
                              void* d_out, int out_size, void* d_ws, size_t ws_size,
                              hipStream_t stream) {
    (void)in_sizes; (void)n_in; (void)out_size;
    const float* X   = (const float*)d_in[0];
    const int*   ind = (const int*)d_in[1];
    const float* W   = (const float*)d_in[2];
    float*       Y   = (float*)d_out;

    const size_t wt_bytes = (size_t)E_ * I_ * J_ * sizeof(u16);  // 512 KB
    const int grid = B_ * E_ * (K_ / 128);                        // 1024

    if (ws_size >= wt_bytes && d_ws != nullptr) {
        u16* Wt = (u16*)d_ws;
        hipLaunchKernelGGL(convert_wt, dim3(E_ * 4), dim3(256), 0, stream, W, Wt);
        hipLaunchKernelGGL((gather_mfma<true>), dim3(grid), dim3(256), 0, stream,
                           X, ind, (const void*)Wt, Y);
    } else {
        hipLaunchKernelGGL((gather_mfma<false>), dim3(grid), dim3(256), 0, stream,
                           X, ind, (const void*)W, Y);
    }
}

// Round 7
// 34.932 us; speedup vs baseline: 1.0674x; 1.0674x over previous
//
#include <hip/hip_runtime.h>
#include <hip/hip_bf16.h>

// Y[b,e,k,j] = sum_i X[b, ind[b,e,k], i] * W[e,i,j]
// X:[B,T,I] f32, ind:[B,E,K] int32, W:[E,I,J] f32 -> Y:[B,E,K,J] f32
#define B_ 8
#define T_ 8192
#define I_ 128
#define E_ 16
#define J_ 128
#define K_ 1024
#define ROWS 64   // k-rows per block

typedef unsigned short u16;
typedef unsigned int   u32;
typedef __attribute__((ext_vector_type(8))) short s8v;   // 8 bf16 = 4 VGPRs
typedef __attribute__((ext_vector_type(4))) float f4v;   // MFMA accumulator

__device__ __forceinline__ u16 f2bf(float f) {
    union { __hip_bfloat16 h; u16 u; } v;
    v.h = __float2bfloat16(f);          // RNE, packs to v_cvt_pk_bf16_f32
    return v.u;
}

// ---- Prepass (r2 verbatim): Wt[e][j][i] = bf16(W[e][i][j]), 128 blocks ----
__global__ void convert_wt(const float* __restrict__ W, u16* __restrict__ Wt) {
    const int t  = blockIdx.x * 256 + threadIdx.x;  // 32768 threads
    const int o8 = t * 8;                           // 8 outputs along i
    const int e  = o8 >> 14;
    const int r  = o8 & 16383;
    const int j  = r >> 7;
    const int i0 = r & 127;
    const float* Wp = W + e * (I_ * J_) + j;        // column j of W[e]
    s8v o;
#pragma unroll
    for (int u = 0; u < 8; ++u)
        o[u] = (short)f2bf(Wp[(i0 + u) * J_]);
    *reinterpret_cast<s8v*>(Wt + o8) = o;
}

// ---- Main (r2 structure): gather + bf16 MFMA GEMM ----
// 256 threads, ROWS=64. LDS: WsT 32KB + Xs 16KB = 48KB -> 3 blocks/CU.
// ONLY changes vs r2: mfma operand order swapped (A=W^T, B=X) and the
// resulting float4 Y stores; native packed bf16 converts.
template<bool PRE>
__global__ __launch_bounds__(256, 3)
void gather_mfma(const float* __restrict__ X, const int* __restrict__ ind,
                 const void* __restrict__ Wsrc, float* __restrict__ Y) {
    __shared__ u16 WsT[I_ * J_];
    __shared__ u16 Xs[ROWS * I_];

    const int t    = threadIdx.x;
    const int wave = t >> 6;
    const int lane = t & 63;

    const int kt = blockIdx.x & 15;      // K_/ROWS = 16
    const int be = blockIdx.x >> 4;
    const int e  = be & (E_ - 1);
    const int b  = be >> 4;
    const int k0 = kt * ROWS;

    // ---- Stage WsT (r2 verbatim): Wt is bf16 [j][i]; swizzled ds_writes ----
    if (PRE) {
        const s8v* Wg = reinterpret_cast<const s8v*>((const u16*)Wsrc + (size_t)e * (I_ * J_));
#pragma unroll
        for (int u = 0; u < 8; ++u) {
            const int c   = t + 256 * u;          // 16B chunk id, 0..2047
            const int row = c >> 4;               // j
            const s8v v = Wg[c];
            *reinterpret_cast<s8v*>((char*)WsT + ((c * 16) ^ ((row & 7) << 4))) = v;
        }
    } else {
        const float* We = (const float*)Wsrc + (size_t)e * (I_ * J_);
#pragma unroll
        for (int u = 0; u < 16; ++u) {
            const int f4i = t + 256 * u;          // float4 id, 0..4095
            const int i   = f4i >> 5;
            const int j0  = (f4i & 31) * 4;
            const float4 w4 = reinterpret_cast<const float4*>(We)[f4i];
            const float ws[4] = {w4.x, w4.y, w4.z, w4.w};
#pragma unroll
            for (int q = 0; q < 4; ++q) {
                const int j = j0 + q;
                *(u16*)((char*)WsT + ((j * 256 + i * 2) ^ ((j & 7) << 4))) = f2bf(ws[q]);
            }
        }
    }

    // ---- Stage Xs (r2 verbatim): gather 64 rows, cvt f32->bf16, swizzled ----
    {
        const int r   = t >> 2;                   // row 0..63
        const int q   = t & 3;                    // 32-elem quarter
        const int idx = ind[(size_t)be * K_ + k0 + r];
        const float4* Xr = reinterpret_cast<const float4*>(X + ((size_t)b * T_ + idx) * I_) + q * 8;
        const int sxr = (r & 7) << 4;
        char* xrow = (char*)Xs + r * 256;
#pragma unroll
        for (int u = 0; u < 4; ++u) {
            const float4 a = Xr[2 * u], c = Xr[2 * u + 1];
            s8v o;
            o[0] = (short)f2bf(a.x); o[1] = (short)f2bf(a.y);
            o[2] = (short)f2bf(a.z); o[3] = (short)f2bf(a.w);
            o[4] = (short)f2bf(c.x); o[5] = (short)f2bf(c.y);
            o[6] = (short)f2bf(c.z); o[7] = (short)f2bf(c.w);
            *reinterpret_cast<s8v*>(xrow + ((q * 64 + u * 16) ^ sxr)) = o;
        }
    }
    __syncthreads();

    // ---- Compute: wave = (k-half rh, j-half jh); 32 k-rows x 64 j-cols ----
    // SWAPPED operands: A = W^T tile (m=j), B = X tile (n=k-row).
    const int rh  = wave >> 1;
    const int jh  = wave & 1;
    const int g   = lane >> 4;
    const int l15 = lane & 15;
    const int sx  = (lane & 7) << 4;

    f4v acc[2][4];
#pragma unroll
    for (int tr = 0; tr < 2; ++tr)
#pragma unroll
        for (int nj = 0; nj < 4; ++nj)
#pragma unroll
            for (int rr = 0; rr < 4; ++rr) acc[tr][nj][rr] = 0.f;

    const char* xb = (const char*)Xs  + (size_t)(rh * 32 + l15) * 256;
    const char* wb = (const char*)WsT + (size_t)(jh * 64 + l15) * 256;
#pragma unroll
    for (int s = 0; s < 4; ++s) {
        const int off = (s * 64 + g * 16) ^ sx;
        const s8v x0 = *reinterpret_cast<const s8v*>(xb + off);
        const s8v x1 = *reinterpret_cast<const s8v*>(xb + 16 * 256 + off);
#pragma unroll
        for (int nj = 0; nj < 4; ++nj) {
            const s8v wf = *reinterpret_cast<const s8v*>(wb + nj * 16 * 256 + off);
            acc[0][nj] = __builtin_amdgcn_mfma_f32_16x16x32_bf16(wf, x0, acc[0][nj], 0, 0, 0);
            acc[1][nj] = __builtin_amdgcn_mfma_f32_16x16x32_bf16(wf, x1, acc[1][nj], 0, 0, 0);
        }
    }

    // ---- Store: D col(l15) = k-row, row(4g+rr) = j -> float4 along j ----
    float* Yb = Y + ((size_t)be * K_ + k0) * J_;
#pragma unroll
    for (int tr = 0; tr < 2; ++tr) {
        float* rowp = Yb + (size_t)(rh * 32 + tr * 16 + l15) * J_ + jh * 64 + g * 4;
#pragma unroll
        for (int nj = 0; nj < 4; ++nj)
            *reinterpret_cast<f4v*>(rowp + nj * 16) = acc[tr][nj];
    }
}

extern "C" void kernel_launch(void* const* d_in, const int* in_sizes, int n_in,
                              void* d_out, int out_size, void* d_ws, size_t ws_size,
                              hipStream_t stream) {
    (void)in_sizes; (void)n_in; (void)out_size;
    const float* X   = (const float*)d_in[0];
    const int*   ind = (const int*)d_in[1];
    const float* W   = (const float*)d_in[2];
    float*       Y   = (float*)d_out;

    const size_t wt_bytes = (size_t)E_ * I_ * J_ * sizeof(u16);  // 512 KB
    const int grid = B_ * E_ * (K_ / ROWS);                       // 2048

    if (ws_size >= wt_bytes && d_ws != nullptr) {
        u16* Wt = (u16*)d_ws;
        hipLaunchKernelGGL(convert_wt, dim3(E_ * I_ * J_ / (256 * 8)), dim3(256), 0, stream, W, Wt);
        hipLaunchKernelGGL((gather_mfma<true>), dim3(grid), dim3(256), 0, stream,
                           X, ind, (const void*)Wt, Y);
    } else {
        hipLaunchKernelGGL((gather_mfma<false>), dim3(grid), dim3(256), 0, stream,
                           X, ind, (const void*)W, Y);
    }
}

// Round 8
// 30.508 us; speedup vs baseline: 1.2221x; 1.1450x over previous
//
#include <hip/hip_runtime.h>

// Y[b,e,k,j] = sum_i X[b, ind[b,e,k], i] * W[e,i,j]
// X:[B,T,I] f32, ind:[B,E,K] int32, W:[E,I,J] f32 -> Y:[B,E,K,J] f32
#define B_ 8
#define T_ 8192
#define I_ 128
#define E_ 16
#define J_ 128
#define K_ 1024
#define ROWS 64   // k-rows per block

typedef unsigned short u16;
typedef unsigned int   u32;
typedef __attribute__((ext_vector_type(8))) short s8v;   // 8 bf16 = 4 VGPRs
typedef __attribute__((ext_vector_type(4))) float f4v;   // MFMA accumulator

__device__ __forceinline__ u16 f2bf(float f) {
    union { float f; u32 u; } v; v.f = f;
    const u32 u = v.u;
    return (u16)((u + 0x7fffu + ((u >> 16) & 1u)) >> 16);  // RNE
}

// ---- Prepass (r2 verbatim): Wt[e][j][i] = bf16(W[e][i][j]) ----
__global__ void convert_wt(const float* __restrict__ W, u16* __restrict__ Wt) {
    const int t  = blockIdx.x * 256 + threadIdx.x;  // 32768 threads
    const int o8 = t * 8;                           // 8 outputs along i
    const int e  = o8 >> 14;
    const int r  = o8 & 16383;
    const int j  = r >> 7;
    const int i0 = r & 127;
    const float* Wp = W + e * (I_ * J_) + j;        // column j of W[e]
    s8v o;
#pragma unroll
    for (int u = 0; u < 8; ++u)
        o[u] = (short)f2bf(Wp[(i0 + u) * J_]);
    *reinterpret_cast<s8v*>(Wt + o8) = o;
}

// ---- Main (r2 verbatim except XCD swizzle): gather + bf16 MFMA GEMM ----
// 256 threads, ROWS=64. LDS: WsT 32KB + Xs 16KB = 48KB -> 3 blocks/CU.
template<bool PRE>
__global__ __launch_bounds__(256, 3)
void gather_mfma(const float* __restrict__ X, const int* __restrict__ ind,
                 const void* __restrict__ Wsrc, float* __restrict__ Y) {
    __shared__ u16 WsT[I_ * J_];
    __shared__ u16 Xs[ROWS * I_];

    const int t    = threadIdx.x;
    const int wave = t >> 6;
    const int lane = t & 63;

    // XCD b-affinity swizzle (ONLY change vs r2): grid=2048, 8 XCDs.
    // XCD x receives orig ≡ x (mod 8) -> bid 256x..256x+255 -> exactly batch b=x.
    // X[b] (4MB) + W image stay resident in that XCD's private L2.
    const int orig = blockIdx.x;
    const int bid  = (orig & 7) * 256 + (orig >> 3);
    const int kt = bid & 15;             // K_/ROWS = 16
    const int be = bid >> 4;
    const int e  = be & (E_ - 1);
    const int b  = be >> 4;
    const int k0 = kt * ROWS;

    // ---- Stage WsT ----
    if (PRE) {
        // Wt is bf16 [j][i]: copy 16B chunks, swizzled dest.
        const s8v* Wg = reinterpret_cast<const s8v*>((const u16*)Wsrc + (size_t)e * (I_ * J_));
#pragma unroll
        for (int u = 0; u < 8; ++u) {
            const int c   = t + 256 * u;          // 16B chunk id, 0..2047
            const int row = c >> 4;               // j
            const s8v v = Wg[c];
            *reinterpret_cast<s8v*>((char*)WsT + ((c * 16) ^ ((row & 7) << 4))) = v;
        }
    } else {
        // Fallback: transpose+convert W[e] (f32 [i][j]) inline.
        const float* We = (const float*)Wsrc + (size_t)e * (I_ * J_);
#pragma unroll
        for (int u = 0; u < 16; ++u) {
            const int f4i = t + 256 * u;          // float4 id, 0..4095
            const int i   = f4i >> 5;
            const int j0  = (f4i & 31) * 4;
            const float4 w4 = reinterpret_cast<const float4*>(We)[f4i];
            const float ws[4] = {w4.x, w4.y, w4.z, w4.w};
#pragma unroll
            for (int q = 0; q < 4; ++q) {
                const int j = j0 + q;
                *(u16*)((char*)WsT + ((j * 256 + i * 2) ^ ((j & 7) << 4))) = f2bf(ws[q]);
            }
        }
    }

    // ---- Stage Xs: gather 64 rows, convert f32->bf16 ----
    {
        const int r   = t >> 2;                   // row 0..63
        const int q   = t & 3;                    // 32-elem quarter
        const int idx = ind[(size_t)be * K_ + k0 + r];
        const float4* Xr = reinterpret_cast<const float4*>(X + ((size_t)b * T_ + idx) * I_) + q * 8;
        const int sx = (r & 7) << 4;
        char* xrow = (char*)Xs + r * 256;
#pragma unroll
        for (int u = 0; u < 4; ++u) {
            const float4 a = Xr[2 * u], c = Xr[2 * u + 1];
            s8v o;
            o[0] = (short)f2bf(a.x); o[1] = (short)f2bf(a.y);
            o[2] = (short)f2bf(a.z); o[3] = (short)f2bf(a.w);
            o[4] = (short)f2bf(c.x); o[5] = (short)f2bf(c.y);
            o[6] = (short)f2bf(c.z); o[7] = (short)f2bf(c.w);
            *reinterpret_cast<s8v*>(xrow + ((q * 64 + u * 16) ^ sx)) = o;
        }
    }
    __syncthreads();

    // ---- Compute: wave = (row-half rh, j-half jh); 32 rows x 64 cols ----
    const int rh  = wave >> 1;
    const int jh  = wave & 1;
    const int g   = lane >> 4;
    const int l15 = lane & 15;
    const int sx  = (lane & 7) << 4;

    f4v acc[2][4];
#pragma unroll
    for (int tr = 0; tr < 2; ++tr)
#pragma unroll
        for (int n = 0; n < 4; ++n)
#pragma unroll
            for (int r = 0; r < 4; ++r) acc[tr][n][r] = 0.f;

    const char* xb = (const char*)Xs  + (size_t)(rh * 32 + l15) * 256;
    const char* wb = (const char*)WsT + (size_t)(jh * 64 + l15) * 256;
#pragma unroll
    for (int s = 0; s < 4; ++s) {
        const int off = (s * 64 + g * 16) ^ sx;
        const s8v a0 = *reinterpret_cast<const s8v*>(xb + off);
        const s8v a1 = *reinterpret_cast<const s8v*>(xb + 16 * 256 + off);
#pragma unroll
        for (int n = 0; n < 4; ++n) {
            const s8v bf = *reinterpret_cast<const s8v*>(wb + n * 16 * 256 + off);
            acc[0][n] = __builtin_amdgcn_mfma_f32_16x16x32_bf16(a0, bf, acc[0][n], 0, 0, 0);
            acc[1][n] = __builtin_amdgcn_mfma_f32_16x16x32_bf16(a1, bf, acc[1][n], 0, 0, 0);
        }
    }

    // ---- Store (C/D: col = lane&15 -> j, row = 4*(lane>>4)+reg -> k) ----
    float* Yb = Y + ((size_t)be * K_ + k0) * J_;
#pragma unroll
    for (int tr = 0; tr < 2; ++tr)
#pragma unroll
        for (int n = 0; n < 4; ++n) {
            const int col = jh * 64 + n * 16 + l15;
            const int row0 = rh * 32 + tr * 16 + g * 4;
#pragma unroll
            for (int r = 0; r < 4; ++r)
                Yb[(size_t)(row0 + r) * J_ + col] = acc[tr][n][r];
        }
}

extern "C" void kernel_launch(void* const* d_in, const int* in_sizes, int n_in,
                              void* d_out, int out_size, void* d_ws, size_t ws_size,
                              hipStream_t stream) {
    (void)in_sizes; (void)n_in; (void)out_size;
    const float* X   = (const float*)d_in[0];
    const int*   ind = (const int*)d_in[1];
    const float* W   = (const float*)d_in[2];
    float*       Y   = (float*)d_out;

    const size_t wt_bytes = (size_t)E_ * I_ * J_ * sizeof(u16);  // 512 KB
    const int grid = B_ * E_ * (K_ / ROWS);                       // 2048

    if (ws_size >= wt_bytes && d_ws != nullptr) {
        u16* Wt = (u16*)d_ws;
        hipLaunchKernelGGL(convert_wt, dim3(E_ * I_ * J_ / (256 * 8)), dim3(256), 0, stream, W, Wt);
        hipLaunchKernelGGL((gather_mfma<true>), dim3(grid), dim3(256), 0, stream,
                           X, ind, (const void*)Wt, Y);
    } else {
        hipLaunchKernelGGL((gather_mfma<false>), dim3(grid), dim3(256), 0, stream,
                           X, ind, (const void*)W, Y);
    }
}